// Round 18
// baseline (1345.359 us; speedup 1.0000x reference)
//
#include <hip/hip_runtime.h>
#include <hip/hip_bf16.h>

// ---------------------------------------------------------------------------
// DR_CRN_Multicause fused forward — round 18: r17 structure made PERSISTENT
//   (grid 256, 8 tiles/block): next tile's X-stage runs inside the current
//   tile's final phase (overlapped with selection/pL2), removing the serial
//   per-round staging + inter-block gaps. f2bf -> native __float2bfloat16.
//   B=131072, N_CONF=512, H1=513(->544), N_REP=256, HP=257(->288), N_TREAT=64
// out (FLOAT32): pred_sel[B] | log_prop[B*64] | mmd[1] | cause[B]
// LDS (156672 B): Cs[0,32768)=[64][256] | Os[32768,65536)=[64][256] |
//   Hs[65536,139264)=[64][576] | headB[139264,156672)=[64][68]f32.
//   Xs[64][512] overlays Cs|Os; Hp[64][320] overlays Hs after it dies.
// Phase safety for the overlapped stage: after B5 the final phase reads only
//   Hp/headB; Xs (=Cs|Os region) is dead -> next-X writes race-free; the
//   loop-top barrier orders them before L1c.
// ---------------------------------------------------------------------------

typedef __attribute__((ext_vector_type(8))) short bf16x8;
typedef __attribute__((ext_vector_type(4))) float f32x4;
typedef __attribute__((ext_vector_type(4))) short s16x4;

#define MFMA16 __builtin_amdgcn_mfma_f32_16x16x32_bf16

__device__ __forceinline__ short f2bf(float f) {
  __hip_bfloat16 h = __float2bfloat16(f);   // RNE, native v_cvt
  return *reinterpret_cast<short*>(&h);
}

// swizzled 16B-group LDS accessors: group' = group ^ (row & 7)
__device__ __forceinline__ const bf16x8* ldsRd8(const short* base, int row,
                                                int grp, int LD) {
  return (const bf16x8*)(base + row * LD + ((grp ^ (row & 7)) << 3));
}
__device__ __forceinline__ short* ldsPtr(short* base, int row, int col, int LD) {
  return base + row * LD + ((((col >> 3) ^ (row & 7)) << 3) | (col & 7));
}

// ---- prep: convert+pad all weights/biases into ws (single launch) ----------
__global__ void prep_weights(const float* __restrict__ W1c, const float* __restrict__ W2c,
                             const float* __restrict__ W1o, const float* __restrict__ W2o,
                             const float* __restrict__ W1p, const float* __restrict__ W2p,
                             const float* __restrict__ Wh,
                             const float* __restrict__ b1c, const float* __restrict__ b1o,
                             const float* __restrict__ b1p,
                             char* __restrict__ ws) {
  int s = blockIdx.x * 256 + threadIdx.x;
  if (s < 960512) {                      // bf16 weight region (shorts)
    float v;
    if (s < 278528)      { int n = s >> 9,        k = s & 511;        v = (n < 513) ? W1c[n * 512 + k] : 0.f; }
    else if (s < 417792) { int i = s - 278528; int n = i / 544, k = i - n * 544; v = (k < 513) ? W2c[n * 513 + k] : 0.f; }
    else if (s < 696320) { int i = s - 417792; int n = i >> 9,  k = i & 511;     v = (n < 513) ? W1o[n * 512 + k] : 0.f; }
    else if (s < 835584) { int i = s - 696320; int n = i / 544, k = i - n * 544; v = (k < 513) ? W2o[n * 513 + k] : 0.f; }
    else if (s < 909312) { int i = s - 835584; int n = i >> 8,  k = i & 255;     v = (n < 257) ? W1p[n * 256 + k] : 0.f; }
    else if (s < 927744) { int i = s - 909312; int n = i / 288, k = i - n * 288; v = (k < 257) ? W2p[n * 257 + k] : 0.f; }
    else                 { v = Wh[s - 927744]; }
    ((short*)ws)[s] = f2bf(v);
  } else if (s < 961888) {               // padded f32 biases
    int j = s - 960512;
    float v;
    if (j < 544)       v = (j < 513) ? b1c[j] : 0.f;
    else if (j < 1088) { int q = j - 544;  v = (q < 513) ? b1o[q] : 0.f; }
    else               { int q = j - 1088; v = (q < 257) ? b1p[q] : 0.f; }
    ((float*)(ws + 1921024))[j] = v;
  }
}

// paired 2x16-col tile over 4 row-groups (swizzled A).
template<int NKT>
__device__ __forceinline__ void pair_mm(const short* __restrict__ W, int ldw,
                                        const short* __restrict__ A, int lda,
                                        int nt0, int l15, int l4,
                                        f32x4 (&acc0)[4], f32x4 (&acc1)[4]) {
  const short* w0 = W + (nt0 * 16 + l15) * ldw + l4 * 8;
  const short* w1 = w0 + 16 * ldw;
  #pragma unroll
  for (int g = 0; g < 4; ++g) {
    acc0[g] = (f32x4){0.f, 0.f, 0.f, 0.f};
    acc1[g] = (f32x4){0.f, 0.f, 0.f, 0.f};
  }
  #pragma unroll
  for (int kt = 0; kt < NKT; ++kt) {
    bf16x8 b0 = *(const bf16x8*)(w0 + kt * 32);
    bf16x8 b1 = *(const bf16x8*)(w1 + kt * 32);
    #pragma unroll
    for (int g = 0; g < 4; ++g) {
      bf16x8 a = *ldsRd8(A, g * 16 + l15, kt * 4 + l4, lda);
      acc0[g] = MFMA16(a, b0, acc0[g], 0, 0, 0);
      acc1[g] = MFMA16(a, b1, acc1[g], 0, 0, 0);
    }
  }
}

__device__ __forceinline__ void store_tile(short* __restrict__ dst, int ldd, int nt,
                                           const float* __restrict__ bias,
                                           const f32x4 (&acc)[4], int l15, int l4,
                                           bool relu) {
  float bi = bias[nt * 16 + l15];
  #pragma unroll
  for (int g = 0; g < 4; ++g)
    #pragma unroll
    for (int r = 0; r < 4; ++r) {
      float v = acc[g][r] + bi;
      if (relu) v = fmaxf(v, 0.f);
      *ldsPtr(dst, g * 16 + l4 * 4 + r, nt * 16 + l15, ldd) = f2bf(v);
    }
}

// single 16-col tile, ONE row-group rg (tail quarter-jobs)
template<int NKT>
__device__ __forceinline__ void single_mm_rg(const short* __restrict__ W, int ldw,
                                             const short* __restrict__ A, int lda,
                                             int nt, int rg, int l15, int l4,
                                             short* __restrict__ dst, int ldd,
                                             const float* __restrict__ bias) {
  f32x4 acc = {0.f, 0.f, 0.f, 0.f};
  const short* w0 = W + (nt * 16 + l15) * ldw + l4 * 8;
  #pragma unroll
  for (int kt = 0; kt < NKT; ++kt) {
    bf16x8 b = *(const bf16x8*)(w0 + kt * 32);
    bf16x8 a = *ldsRd8(A, rg * 16 + l15, kt * 4 + l4, lda);
    acc = MFMA16(a, b, acc, 0, 0, 0);
  }
  float bi = bias[nt * 16 + l15];
  #pragma unroll
  for (int r = 0; r < 4; ++r)
    *ldsPtr(dst, rg * 16 + l4 * 4 + r, nt * 16 + l15, ldd) = f2bf(fmaxf(acc[r] + bi, 0.f));
}

// zero one 16-col tile for one row-group
__device__ __forceinline__ void zero_tile_rg(short* __restrict__ dst, int ldd,
                                             int nt, int rg, int l15, int l4) {
  #pragma unroll
  for (int r = 0; r < 4; ++r)
    *ldsPtr(dst, rg * 16 + l4 * 4 + r, nt * 16 + l15, ldd) = 0;
}

__global__ __launch_bounds__(512, 1)
void fused_main(const float* __restrict__ x, const int* __restrict__ cause,
                const char* __restrict__ ws,
                const float* __restrict__ b2c, const float* __restrict__ b2o,
                const float* __restrict__ b2p, const float* __restrict__ bh,
                float* __restrict__ out) {
  const short* W1cb = (const short*)(ws);
  const short* W2cb = (const short*)(ws + 557056);
  const short* W1ob = (const short*)(ws + 835584);
  const short* W2ob = (const short*)(ws + 1392640);
  const short* W1pb = (const short*)(ws + 1671168);
  const short* W2pb = (const short*)(ws + 1818624);
  const short* Whb  = (const short*)(ws + 1855488);
  const float* b1cp = (const float*)(ws + 1921024);
  const float* b1op = (const float*)(ws + 1923200);
  const float* b1pp = (const float*)(ws + 1925376);

  extern __shared__ __align__(16) char lds[];
  short* Cs    = (short*)lds;             // [64][256]
  short* Os    = (short*)(lds + 32768);   // [64][256]
  short* Hs    = (short*)(lds + 65536);   // [64][576]
  short* Xs    = (short*)lds;             // [64][512] overlays Cs|Os exactly
  short* Hp    = (short*)(lds + 65536);   // [64][320] (overlays Hs after dead)
  float* headB = (float*)(lds + 139264);  // [64][68] f32 — own region

  const int tid  = threadIdx.x;
  const int lane = tid & 63;
  const int wid  = tid >> 6;             // 0..7
  const int l15  = lane & 15;
  const int l4   = lane >> 4;            // 0..3

  auto stageX = [&](size_t g0) {
    const f32x4* xsrc = (const f32x4*)(x + g0 * 512);
    for (int i = tid; i < 8192; i += 512) {   // 64 rows * 128 float4
      f32x4 v = __builtin_nontemporal_load(xsrc + i);
      int r = i >> 7, c = i & 127;
      s16x4 p;
      p.x = f2bf(v.x); p.y = f2bf(v.y); p.z = f2bf(v.z); p.w = f2bf(v.w);
      int grp = (c >> 1) ^ (r & 7);       // 16B group = 2 float4-cols
      *(s16x4*)(Xs + r * 512 + (grp << 3) + ((c & 1) << 2)) = p;
    }
  };

  // prologue: stage tile 0
  stageX((size_t)blockIdx.x * 64);

  #pragma unroll 1
  for (int it = 0; it < 8; ++it) {
    const size_t grow0 = ((size_t)it * 256 + blockIdx.x) * 64;
    __syncthreads();   // loop-top: Xs ready (prologue or prev final phase)

    // ---- L1c: Hs = relu(X @ W1c^T + b1c); 16 pairs (2/wave) + tail jobs ---
    for (int p = wid; p < 16; p += 8) {
      f32x4 a0[4], a1[4];
      pair_mm<16>(W1cb, 512, Xs, 512, 2 * p, l15, l4, a0, a1);
      store_tile(Hs, 576, 2 * p,     b1cp, a0, l15, l4, true);
      store_tile(Hs, 576, 2 * p + 1, b1cp, a1, l15, l4, true);
    }
    if (wid < 4)  // tile 32 (only row 512 real; 513-527 auto-zero)
      single_mm_rg<16>(W1cb, 512, Xs, 512, 32, wid, l15, l4, Hs, 576, b1cp);
    else          // tile 33: all-zero
      zero_tile_rg(Hs, 576, 33, wid - 4, l15, l4);
    __syncthreads();   // B1: H_c complete

    // ---- L2c: crep = Hs @ W2c^T + b2c; 8 pairs = 1/wave; kept in regs ----
    s16x4 crp[2][4];   // [jj][g]: nt = 2*wid + jj
    {
      f32x4 a0[4], a1[4];
      pair_mm<17>(W2cb, 544, Hs, 576, 2 * wid, l15, l4, a0, a1);
      float bi0 = b2c[wid * 32 + l15], bi1 = b2c[wid * 32 + 16 + l15];
      #pragma unroll
      for (int g = 0; g < 4; ++g) {
        s16x4 q0, q1;
        #pragma unroll
        for (int r = 0; r < 4; ++r) {
          q0[r] = f2bf(a0[g][r] + bi0);
          q1[r] = f2bf(a1[g][r] + bi1);
        }
        crp[0][g] = q0; crp[1][g] = q1;
      }
    }
    __syncthreads();   // B2: Hs reads done -> L1o may overwrite

    // ---- L1o: Hs = relu(X @ W1o^T + b1o); roles mirrored for tail ----
    for (int p = wid; p < 16; p += 8) {
      f32x4 a0[4], a1[4];
      pair_mm<16>(W1ob, 512, Xs, 512, 2 * p, l15, l4, a0, a1);
      store_tile(Hs, 576, 2 * p,     b1op, a0, l15, l4, true);
      store_tile(Hs, 576, 2 * p + 1, b1op, a1, l15, l4, true);
    }
    if (wid >= 4)
      single_mm_rg<16>(W1ob, 512, Xs, 512, 32, wid - 4, l15, l4, Hs, 576, b1op);
    else
      zero_tile_rg(Hs, 576, 33, wid, l15, l4);
    __syncthreads();   // B3: H_o complete; Xs dead everywhere

    // ---- flush crep -> Cs (region now free) ----
    #pragma unroll
    for (int jj = 0; jj < 2; ++jj) {
      int nt = 2 * wid + jj;
      #pragma unroll
      for (int g = 0; g < 4; ++g)
        #pragma unroll
        for (int r = 0; r < 4; ++r)
          *ldsPtr(Cs, g * 16 + l4 * 4 + r, nt * 16 + l15, 256) = crp[jj][g][r];
    }

    // ---- L2o: Os = Hs @ W2o^T + b2o; 1 pair/wave ----
    {
      f32x4 a0[4], a1[4];
      pair_mm<17>(W2ob, 544, Hs, 576, 2 * wid, l15, l4, a0, a1);
      store_tile(Os, 256, 2 * wid,     b2o, a0, l15, l4, false);
      store_tile(Os, 256, 2 * wid + 1, b2o, a1, l15, l4, false);
    }
    __syncthreads();   // B4: Cs+Os complete; Hs dead

    // ==== MERGED PHASE 5: head (-> headB) + propensity L1 (-> Hp) ====
    {
      const int g = wid >> 1;
      const int rb = g * 16;
      const int ntb = (wid & 1) * 2;
      bf16x8 acf[16];
      #pragma unroll
      for (int kt = 0; kt < 8; ++kt) {
        acf[kt]     = *ldsRd8(Cs, rb + l15, kt * 4 + l4, 256);
        acf[kt + 8] = *ldsRd8(Os, rb + l15, kt * 4 + l4, 256);
      }
      f32x4 hacc[2] = {{0.f,0.f,0.f,0.f},{0.f,0.f,0.f,0.f}};
      #pragma unroll
      for (int j = 0; j < 2; ++j) {
        const short* w0 = Whb + ((ntb + j) * 16 + l15) * 512 + l4 * 8;
        #pragma unroll
        for (int kt = 0; kt < 16; ++kt)
          hacc[j] = MFMA16(acf[kt], *(const bf16x8*)(w0 + kt * 32), hacc[j], 0, 0, 0);
      }
      #pragma unroll
      for (int j = 0; j < 2; ++j)
        #pragma unroll
        for (int r = 0; r < 4; ++r)
          headB[(rb + l4 * 4 + r) * 68 + (ntb + j) * 16 + l15] = hacc[j][r];
    }
    {
      f32x4 a0[4], a1[4];
      pair_mm<8>(W1pb, 256, Cs, 256, 2 * wid, l15, l4, a0, a1);
      store_tile(Hp, 320, 2 * wid,     b1pp, a0, l15, l4, true);
      store_tile(Hp, 320, 2 * wid + 1, b1pp, a1, l15, l4, true);
    }
    if (wid < 4)  // tile 16 (only row 256 real; 257-271 auto-zero)
      single_mm_rg<8>(W1pb, 256, Cs, 256, 16, wid, l15, l4, Hp, 320, b1pp);
    else          // tile 17: all-zero
      zero_tile_rg(Hp, 320, 17, wid - 4, l15, l4);
    __syncthreads();   // B5: headB + Hp complete; Cs/Os (Xs region) dead

    // ==== FINAL PHASE: selection (waves 4-7) + pL2/softmax (waves 0-3)
    //      + overlapped stage of NEXT tile's X into the dead Xs region ====
    if (wid >= 4 && lane < 16) {
      int row = (wid - 4) * 16 + lane;
      size_t gr = grow0 + row;
      int cv = cause[gr];
      out[gr] = headB[row * 68 + cv] + bh[cv];
      out[(size_t)8519681 + gr] = (float)cv;
    }
    if (wid < 4) {
      const int rb = wid * 16;
      f32x4 pl[4];
      {
        bf16x8 ahp[9];
        #pragma unroll
        for (int kt = 0; kt < 9; ++kt)
          ahp[kt] = *ldsRd8(Hp, rb + l15, kt * 4 + l4, 320);
        #pragma unroll
        for (int nt = 0; nt < 4; ++nt) {
          f32x4 a0 = {0.f, 0.f, 0.f, 0.f};
          const short* w0 = W2pb + (nt * 16 + l15) * 288 + l4 * 8;
          #pragma unroll
          for (int kt = 0; kt < 9; ++kt)
            a0 = MFMA16(ahp[kt], *(const bf16x8*)(w0 + kt * 32), a0, 0, 0, 0);
          float bi = b2p[nt * 16 + l15];
          #pragma unroll
          for (int r = 0; r < 4; ++r) a0[r] += bi;
          pl[nt] = a0;
        }
      }
      #pragma unroll
      for (int r = 0; r < 4; ++r) {
        float m = fmaxf(fmaxf(pl[0][r], pl[1][r]), fmaxf(pl[2][r], pl[3][r]));
        m = fmaxf(m, __shfl_xor(m, 1, 64));
        m = fmaxf(m, __shfl_xor(m, 2, 64));
        m = fmaxf(m, __shfl_xor(m, 4, 64));
        m = fmaxf(m, __shfl_xor(m, 8, 64));
        float s = __expf(pl[0][r] - m) + __expf(pl[1][r] - m)
                + __expf(pl[2][r] - m) + __expf(pl[3][r] - m);
        s += __shfl_xor(s, 1, 64);
        s += __shfl_xor(s, 2, 64);
        s += __shfl_xor(s, 4, 64);
        s += __shfl_xor(s, 8, 64);
        float lse = m + __logf(s);
        size_t gr = grow0 + rb + l4 * 4 + r;
        float* o1 = out + 131072 + gr * 64;
        #pragma unroll
        for (int nt = 0; nt < 4; ++nt)
          o1[nt * 16 + l15] = pl[nt][r] - lse;
      }
    }
    if (it < 7)
      stageX(((size_t)(it + 1) * 256 + blockIdx.x) * 64);
  }
  if (blockIdx.x == 0 && tid == 0) out[8519680] = 0.0f;   // mmd
}

extern "C" void kernel_launch(void* const* d_in, const int* in_sizes, int n_in,
                              void* d_out, int out_size, void* d_ws, size_t ws_size,
                              hipStream_t stream) {
  (void)in_sizes; (void)n_in; (void)out_size; (void)ws_size;
  const float* x    = (const float*)d_in[0];
  const int*   cause= (const int*)  d_in[1];
  const float* W1c  = (const float*)d_in[2];
  const float* b1c  = (const float*)d_in[3];
  const float* W2c  = (const float*)d_in[4];
  const float* b2c  = (const float*)d_in[5];
  const float* W1o  = (const float*)d_in[6];
  const float* b1o  = (const float*)d_in[7];
  const float* W2o  = (const float*)d_in[8];
  const float* b2o  = (const float*)d_in[9];
  const float* W1p  = (const float*)d_in[10];
  const float* b1p  = (const float*)d_in[11];
  const float* W2p  = (const float*)d_in[12];
  const float* b2p  = (const float*)d_in[13];
  const float* Wh   = (const float*)d_in[14];
  const float* bh   = (const float*)d_in[15];
  char* ws = (char*)d_ws;

  prep_weights<<<3758, 256, 0, stream>>>(W1c, W2c, W1o, W2o, W1p, W2p, Wh,
                                         b1c, b1o, b1p, ws);

  (void)hipFuncSetAttribute((const void*)fused_main,
                            hipFuncAttributeMaxDynamicSharedMemorySize, 156672);
  fused_main<<<256, 512, 156672, stream>>>(x, cause, ws, b2c, b2o, b2p, bh,
                                           (float*)d_out);
}

// Round 19
// 564.013 us; speedup vs baseline: 2.3853x; 2.3853x over previous
//
#include <hip/hip_runtime.h>

// ---------------------------------------------------------------------------
// DR_CRN_Multicause fused forward — round 19: REVERT to r14 (best, 563us).
//   r18's persistent-grid regressed 2.4x (spill + L2 thrash); restoring the
//   verified best: 8 waves/block, 64-row tile, pair tiles over 4 row-groups,
//   XOR swizzle, balanced phase splits with micro-tails, reg-parked crep.
//   B=131072, N_CONF=512, H1=513(->544), N_REP=256, HP=257(->288), N_TREAT=64
// out (FLOAT32): pred_sel[B] | log_prop[B*64] | mmd[1] | cause[B]
// LDS (139264 B): Cs[0,32768)=[64][256] | Os[32768,65536)=[64][256] |
//   Hs[65536,139264)=[64][576]; Xs[64][512] overlays Cs|Os exactly;
//   headB[64][68]f32 / Hp[64][320] overlay Hs after it dies.
// ---------------------------------------------------------------------------

typedef __attribute__((ext_vector_type(8))) short bf16x8;
typedef __attribute__((ext_vector_type(4))) float f32x4;
typedef __attribute__((ext_vector_type(4))) short s16x4;

#define MFMA16 __builtin_amdgcn_mfma_f32_16x16x32_bf16

__device__ __forceinline__ short f2bf(float f) {
  union { float f; unsigned u; } v; v.f = f;
  return (short)((v.u + 0x7FFFu + ((v.u >> 16) & 1u)) >> 16);  // RNE
}

// swizzled 16B-group LDS accessors: group' = group ^ (row & 7)
__device__ __forceinline__ const bf16x8* ldsRd8(const short* base, int row,
                                                int grp, int LD) {
  return (const bf16x8*)(base + row * LD + ((grp ^ (row & 7)) << 3));
}
__device__ __forceinline__ short* ldsPtr(short* base, int row, int col, int LD) {
  return base + row * LD + ((((col >> 3) ^ (row & 7)) << 3) | (col & 7));
}

// ---- prep: convert+pad all weights/biases into ws (single launch) ----------
__global__ void prep_weights(const float* __restrict__ W1c, const float* __restrict__ W2c,
                             const float* __restrict__ W1o, const float* __restrict__ W2o,
                             const float* __restrict__ W1p, const float* __restrict__ W2p,
                             const float* __restrict__ Wh,
                             const float* __restrict__ b1c, const float* __restrict__ b1o,
                             const float* __restrict__ b1p,
                             char* __restrict__ ws) {
  int s = blockIdx.x * 256 + threadIdx.x;
  if (s < 960512) {                      // bf16 weight region (shorts)
    float v;
    if (s < 278528)      { int n = s >> 9,        k = s & 511;        v = (n < 513) ? W1c[n * 512 + k] : 0.f; }
    else if (s < 417792) { int i = s - 278528; int n = i / 544, k = i - n * 544; v = (k < 513) ? W2c[n * 513 + k] : 0.f; }
    else if (s < 696320) { int i = s - 417792; int n = i >> 9,  k = i & 511;     v = (n < 513) ? W1o[n * 512 + k] : 0.f; }
    else if (s < 835584) { int i = s - 696320; int n = i / 544, k = i - n * 544; v = (k < 513) ? W2o[n * 513 + k] : 0.f; }
    else if (s < 909312) { int i = s - 835584; int n = i >> 8,  k = i & 255;     v = (n < 257) ? W1p[n * 256 + k] : 0.f; }
    else if (s < 927744) { int i = s - 909312; int n = i / 288, k = i - n * 288; v = (k < 257) ? W2p[n * 257 + k] : 0.f; }
    else                 { v = Wh[s - 927744]; }
    ((short*)ws)[s] = f2bf(v);
  } else if (s < 961888) {               // padded f32 biases
    int j = s - 960512;
    float v;
    if (j < 544)       v = (j < 513) ? b1c[j] : 0.f;
    else if (j < 1088) { int q = j - 544;  v = (q < 513) ? b1o[q] : 0.f; }
    else               { int q = j - 1088; v = (q < 257) ? b1p[q] : 0.f; }
    ((float*)(ws + 1921024))[j] = v;
  }
}

// paired 2x16-col tile over 4 row-groups (swizzled A).
template<int NKT>
__device__ __forceinline__ void pair_mm(const short* __restrict__ W, int ldw,
                                        const short* __restrict__ A, int lda,
                                        int nt0, int l15, int l4,
                                        f32x4 (&acc0)[4], f32x4 (&acc1)[4]) {
  const short* w0 = W + (nt0 * 16 + l15) * ldw + l4 * 8;
  const short* w1 = w0 + 16 * ldw;
  #pragma unroll
  for (int g = 0; g < 4; ++g) {
    acc0[g] = (f32x4){0.f, 0.f, 0.f, 0.f};
    acc1[g] = (f32x4){0.f, 0.f, 0.f, 0.f};
  }
  #pragma unroll
  for (int kt = 0; kt < NKT; ++kt) {
    bf16x8 b0 = *(const bf16x8*)(w0 + kt * 32);
    bf16x8 b1 = *(const bf16x8*)(w1 + kt * 32);
    #pragma unroll
    for (int g = 0; g < 4; ++g) {
      bf16x8 a = *ldsRd8(A, g * 16 + l15, kt * 4 + l4, lda);
      acc0[g] = MFMA16(a, b0, acc0[g], 0, 0, 0);
      acc1[g] = MFMA16(a, b1, acc1[g], 0, 0, 0);
    }
  }
}

__device__ __forceinline__ void store_tile(short* __restrict__ dst, int ldd, int nt,
                                           const float* __restrict__ bias,
                                           const f32x4 (&acc)[4], int l15, int l4,
                                           bool relu) {
  float bi = bias[nt * 16 + l15];
  #pragma unroll
  for (int g = 0; g < 4; ++g)
    #pragma unroll
    for (int r = 0; r < 4; ++r) {
      float v = acc[g][r] + bi;
      if (relu) v = fmaxf(v, 0.f);
      *ldsPtr(dst, g * 16 + l4 * 4 + r, nt * 16 + l15, ldd) = f2bf(v);
    }
}

// single 16-col tile, ONE row-group rg (tail quarter-jobs)
template<int NKT>
__device__ __forceinline__ void single_mm_rg(const short* __restrict__ W, int ldw,
                                             const short* __restrict__ A, int lda,
                                             int nt, int rg, int l15, int l4,
                                             short* __restrict__ dst, int ldd,
                                             const float* __restrict__ bias) {
  f32x4 acc = {0.f, 0.f, 0.f, 0.f};
  const short* w0 = W + (nt * 16 + l15) * ldw + l4 * 8;
  #pragma unroll
  for (int kt = 0; kt < NKT; ++kt) {
    bf16x8 b = *(const bf16x8*)(w0 + kt * 32);
    bf16x8 a = *ldsRd8(A, rg * 16 + l15, kt * 4 + l4, lda);
    acc = MFMA16(a, b, acc, 0, 0, 0);
  }
  float bi = bias[nt * 16 + l15];
  #pragma unroll
  for (int r = 0; r < 4; ++r)
    *ldsPtr(dst, rg * 16 + l4 * 4 + r, nt * 16 + l15, ldd) = f2bf(fmaxf(acc[r] + bi, 0.f));
}

// zero one 16-col tile for one row-group
__device__ __forceinline__ void zero_tile_rg(short* __restrict__ dst, int ldd,
                                             int nt, int rg, int l15, int l4) {
  #pragma unroll
  for (int r = 0; r < 4; ++r)
    *ldsPtr(dst, rg * 16 + l4 * 4 + r, nt * 16 + l15, ldd) = 0;
}

__global__ __launch_bounds__(512, 1)
void fused_main(const float* __restrict__ x, const int* __restrict__ cause,
                const char* __restrict__ ws,
                const float* __restrict__ b2c, const float* __restrict__ b2o,
                const float* __restrict__ b2p, const float* __restrict__ bh,
                float* __restrict__ out) {
  const short* W1cb = (const short*)(ws);
  const short* W2cb = (const short*)(ws + 557056);
  const short* W1ob = (const short*)(ws + 835584);
  const short* W2ob = (const short*)(ws + 1392640);
  const short* W1pb = (const short*)(ws + 1671168);
  const short* W2pb = (const short*)(ws + 1818624);
  const short* Whb  = (const short*)(ws + 1855488);
  const float* b1cp = (const float*)(ws + 1921024);
  const float* b1op = (const float*)(ws + 1923200);
  const float* b1pp = (const float*)(ws + 1925376);

  extern __shared__ __align__(16) char lds[];
  short* Cs    = (short*)lds;             // [64][256]
  short* Os    = (short*)(lds + 32768);   // [64][256]
  short* Hs    = (short*)(lds + 65536);   // [64][576]
  short* Xs    = (short*)lds;             // [64][512] overlays Cs|Os exactly
  float* headB = (float*)(lds + 65536);   // [64][68] f32 (after Hs dead)
  short* Hp    = (short*)(lds + 65536);   // [64][320]    (after headB dead)

  const int tid  = threadIdx.x;
  const int lane = tid & 63;
  const int wid  = tid >> 6;             // 0..7
  const int l15  = lane & 15;
  const int l4   = lane >> 4;            // 0..3
  const size_t grow0 = (size_t)blockIdx.x * 64;

  // ---- stage X (f32 -> bf16, swizzled), nontemporal ----
  {
    const f32x4* xsrc = (const f32x4*)(x + grow0 * 512);
    for (int i = tid; i < 8192; i += 512) {   // 64 rows * 128 float4
      f32x4 v = __builtin_nontemporal_load(xsrc + i);
      int r = i >> 7, c = i & 127;
      s16x4 p;
      p.x = f2bf(v.x); p.y = f2bf(v.y); p.z = f2bf(v.z); p.w = f2bf(v.w);
      int grp = (c >> 1) ^ (r & 7);       // 16B group = 2 float4-cols
      *(s16x4*)(Xs + r * 512 + (grp << 3) + ((c & 1) << 2)) = p;
    }
  }
  __syncthreads();   // B0: X staged

  // ---- L1c: Hs = relu(X @ W1c^T + b1c); 16 pairs (2/wave) + tail jobs ----
  for (int p = wid; p < 16; p += 8) {
    f32x4 a0[4], a1[4];
    pair_mm<16>(W1cb, 512, Xs, 512, 2 * p, l15, l4, a0, a1);
    store_tile(Hs, 576, 2 * p,     b1cp, a0, l15, l4, true);
    store_tile(Hs, 576, 2 * p + 1, b1cp, a1, l15, l4, true);
  }
  if (wid < 4)  // tile 32 (only row 512 real; 513-527 auto-zero via padded W)
    single_mm_rg<16>(W1cb, 512, Xs, 512, 32, wid, l15, l4, Hs, 576, b1cp);
  else          // tile 33: all-zero (rows 528-543 of padded H1)
    zero_tile_rg(Hs, 576, 33, wid - 4, l15, l4);
  __syncthreads();   // B1: H_c complete

  // ---- L2c: crep = Hs @ W2c^T + b2c; 8 pairs = 1/wave; kept in regs ----
  s16x4 crp[2][4];   // [jj][g]: nt = 2*wid + jj
  {
    f32x4 a0[4], a1[4];
    pair_mm<17>(W2cb, 544, Hs, 576, 2 * wid, l15, l4, a0, a1);
    float bi0 = b2c[wid * 32 + l15], bi1 = b2c[wid * 32 + 16 + l15];
    #pragma unroll
    for (int g = 0; g < 4; ++g) {
      s16x4 q0, q1;
      #pragma unroll
      for (int r = 0; r < 4; ++r) {
        q0[r] = f2bf(a0[g][r] + bi0);
        q1[r] = f2bf(a1[g][r] + bi1);
      }
      crp[0][g] = q0; crp[1][g] = q1;
    }
  }
  __syncthreads();   // B2: Hs reads done -> L1o may overwrite

  // ---- L1o: Hs = relu(X @ W1o^T + b1o); roles mirrored for tail ----
  for (int p = wid; p < 16; p += 8) {
    f32x4 a0[4], a1[4];
    pair_mm<16>(W1ob, 512, Xs, 512, 2 * p, l15, l4, a0, a1);
    store_tile(Hs, 576, 2 * p,     b1op, a0, l15, l4, true);
    store_tile(Hs, 576, 2 * p + 1, b1op, a1, l15, l4, true);
  }
  if (wid >= 4)
    single_mm_rg<16>(W1ob, 512, Xs, 512, 32, wid - 4, l15, l4, Hs, 576, b1op);
  else
    zero_tile_rg(Hs, 576, 33, wid, l15, l4);
  __syncthreads();   // B3: H_o complete; Xs dead everywhere

  // ---- flush crep -> Cs (region now free) ----
  #pragma unroll
  for (int jj = 0; jj < 2; ++jj) {
    int nt = 2 * wid + jj;
    #pragma unroll
    for (int g = 0; g < 4; ++g)
      #pragma unroll
      for (int r = 0; r < 4; ++r)
        *ldsPtr(Cs, g * 16 + l4 * 4 + r, nt * 16 + l15, 256) = crp[jj][g][r];
  }

  // ---- L2o: Os = Hs @ W2o^T + b2o; 1 pair/wave ----
  {
    f32x4 a0[4], a1[4];
    pair_mm<17>(W2ob, 544, Hs, 576, 2 * wid, l15, l4, a0, a1);
    store_tile(Os, 256, 2 * wid,     b2o, a0, l15, l4, false);
    store_tile(Os, 256, 2 * wid + 1, b2o, a1, l15, l4, false);
  }
  __syncthreads();   // B4: Cs+Os complete; Hs dead

  // ---- head: wave pair (g = wid>>1) shares 16-row group, splits 4 nt 2/2 --
  {
    const int g = wid >> 1;
    const int rb = g * 16;
    const int ntb = (wid & 1) * 2;
    bf16x8 acf[16];
    #pragma unroll
    for (int kt = 0; kt < 8; ++kt) {
      acf[kt]     = *ldsRd8(Cs, rb + l15, kt * 4 + l4, 256);
      acf[kt + 8] = *ldsRd8(Os, rb + l15, kt * 4 + l4, 256);
    }
    f32x4 hacc[2] = {{0.f,0.f,0.f,0.f},{0.f,0.f,0.f,0.f}};
    #pragma unroll
    for (int j = 0; j < 2; ++j) {
      const short* w0 = Whb + ((ntb + j) * 16 + l15) * 512 + l4 * 8;
      #pragma unroll
      for (int kt = 0; kt < 16; ++kt)
        hacc[j] = MFMA16(acf[kt], *(const bf16x8*)(w0 + kt * 32), hacc[j], 0, 0, 0);
    }
    // headB overlays Hs region (dead after B4); unswizzled f32
    #pragma unroll
    for (int j = 0; j < 2; ++j)
      #pragma unroll
      for (int r = 0; r < 4; ++r)
        headB[(rb + l4 * 4 + r) * 68 + (ntb + j) * 16 + l15] = hacc[j][r];
  }
  __syncthreads();   // B5: headB complete (nt halves from both waves of pair)

  // one-hot selection + cause passthrough: waves 0..3 handle 16 rows each
  if (wid < 4 && lane < 16) {
    int row = wid * 16 + lane;
    size_t gr = grow0 + row;
    int cv = cause[gr];
    out[gr] = headB[row * 68 + cv] + bh[cv];
    out[(size_t)8519681 + gr] = (float)cv;
  }
  __syncthreads();   // B6: selection reads done -> Hp may overwrite

  // ---- propensity L1: Hp = relu(Cs @ W1p^T + b1p); 8 pairs + tail jobs ----
  {
    f32x4 a0[4], a1[4];
    pair_mm<8>(W1pb, 256, Cs, 256, 2 * wid, l15, l4, a0, a1);
    store_tile(Hp, 320, 2 * wid,     b1pp, a0, l15, l4, true);
    store_tile(Hp, 320, 2 * wid + 1, b1pp, a1, l15, l4, true);
  }
  if (wid < 4)  // tile 16 (only row 256 real; 257-271 auto-zero)
    single_mm_rg<8>(W1pb, 256, Cs, 256, 16, wid, l15, l4, Hp, 320, b1pp);
  else          // tile 17: all-zero
    zero_tile_rg(Hp, 320, 17, wid - 4, l15, l4);
  __syncthreads();   // B7: Hp complete

  // ---- propensity L2 + log_softmax: waves 0..3, one 16-row group each ----
  if (wid < 4) {
    const int rb = wid * 16;
    f32x4 pl[4];
    {
      bf16x8 ahp[9];
      #pragma unroll
      for (int kt = 0; kt < 9; ++kt)
        ahp[kt] = *ldsRd8(Hp, rb + l15, kt * 4 + l4, 320);
      #pragma unroll
      for (int nt = 0; nt < 4; ++nt) {
        f32x4 a0 = {0.f, 0.f, 0.f, 0.f};
        const short* w0 = W2pb + (nt * 16 + l15) * 288 + l4 * 8;
        #pragma unroll
        for (int kt = 0; kt < 9; ++kt)
          a0 = MFMA16(ahp[kt], *(const bf16x8*)(w0 + kt * 32), a0, 0, 0, 0);
        float bi = b2p[nt * 16 + l15];
        #pragma unroll
        for (int r = 0; r < 4; ++r) a0[r] += bi;
        pl[nt] = a0;
      }
    }
    #pragma unroll
    for (int r = 0; r < 4; ++r) {
      float m = fmaxf(fmaxf(pl[0][r], pl[1][r]), fmaxf(pl[2][r], pl[3][r]));
      m = fmaxf(m, __shfl_xor(m, 1, 64));
      m = fmaxf(m, __shfl_xor(m, 2, 64));
      m = fmaxf(m, __shfl_xor(m, 4, 64));
      m = fmaxf(m, __shfl_xor(m, 8, 64));
      float s = __expf(pl[0][r] - m) + __expf(pl[1][r] - m)
              + __expf(pl[2][r] - m) + __expf(pl[3][r] - m);
      s += __shfl_xor(s, 1, 64);
      s += __shfl_xor(s, 2, 64);
      s += __shfl_xor(s, 4, 64);
      s += __shfl_xor(s, 8, 64);
      float lse = m + __logf(s);
      size_t gr = grow0 + rb + l4 * 4 + r;
      float* o1 = out + 131072 + gr * 64;
      #pragma unroll
      for (int nt = 0; nt < 4; ++nt)
        o1[nt * 16 + l15] = pl[nt][r] - lse;
    }
  }
  if (blockIdx.x == 0 && tid == 0) out[8519680] = 0.0f;   // mmd
}

extern "C" void kernel_launch(void* const* d_in, const int* in_sizes, int n_in,
                              void* d_out, int out_size, void* d_ws, size_t ws_size,
                              hipStream_t stream) {
  (void)in_sizes; (void)n_in; (void)out_size; (void)ws_size;
  const float* x    = (const float*)d_in[0];
  const int*   cause= (const int*)  d_in[1];
  const float* W1c  = (const float*)d_in[2];
  const float* b1c  = (const float*)d_in[3];
  const float* W2c  = (const float*)d_in[4];
  const float* b2c  = (const float*)d_in[5];
  const float* W1o  = (const float*)d_in[6];
  const float* b1o  = (const float*)d_in[7];
  const float* W2o  = (const float*)d_in[8];
  const float* b2o  = (const float*)d_in[9];
  const float* W1p  = (const float*)d_in[10];
  const float* b1p  = (const float*)d_in[11];
  const float* W2p  = (const float*)d_in[12];
  const float* b2p  = (const float*)d_in[13];
  const float* Wh   = (const float*)d_in[14];
  const float* bh   = (const float*)d_in[15];
  char* ws = (char*)d_ws;

  prep_weights<<<3758, 256, 0, stream>>>(W1c, W2c, W1o, W2o, W1p, W2p, Wh,
                                         b1c, b1o, b1p, ws);

  (void)hipFuncSetAttribute((const void*)fused_main,
                            hipFuncAttributeMaxDynamicSharedMemorySize, 139264);
  fused_main<<<2048, 512, 139264, stream>>>(x, cause, ws, b2c, b2o, b2p, bh,
                                            (float*)d_out);
}

// Round 20
// 554.836 us; speedup vs baseline: 2.4248x; 1.0165x over previous
//
#include <hip/hip_runtime.h>
#include <hip/hip_bf16.h>

// ---------------------------------------------------------------------------
// DR_CRN_Multicause fused forward — round 20: r14 base (best, 563-564us) with
//   ONE change: f2bf manual 5-op RNE -> native __float2bfloat16 (single
//   v_cvt). Everything else byte-identical to r19.
//   8 waves/block, 64-row tile, pair tiles over 4 row-groups, XOR swizzle,
//   balanced phase splits with micro-tails, reg-parked crep.
//   B=131072, N_CONF=512, H1=513(->544), N_REP=256, HP=257(->288), N_TREAT=64
// out (FLOAT32): pred_sel[B] | log_prop[B*64] | mmd[1] | cause[B]
// LDS (139264 B): Cs[0,32768)=[64][256] | Os[32768,65536)=[64][256] |
//   Hs[65536,139264)=[64][576]; Xs[64][512] overlays Cs|Os exactly;
//   headB[64][68]f32 / Hp[64][320] overlay Hs after it dies.
// ---------------------------------------------------------------------------

typedef __attribute__((ext_vector_type(8))) short bf16x8;
typedef __attribute__((ext_vector_type(4))) float f32x4;
typedef __attribute__((ext_vector_type(4))) short s16x4;

#define MFMA16 __builtin_amdgcn_mfma_f32_16x16x32_bf16

__device__ __forceinline__ short f2bf(float f) {
  __hip_bfloat16 h = __float2bfloat16(f);   // RNE, native v_cvt
  return *reinterpret_cast<short*>(&h);
}

// swizzled 16B-group LDS accessors: group' = group ^ (row & 7)
__device__ __forceinline__ const bf16x8* ldsRd8(const short* base, int row,
                                                int grp, int LD) {
  return (const bf16x8*)(base + row * LD + ((grp ^ (row & 7)) << 3));
}
__device__ __forceinline__ short* ldsPtr(short* base, int row, int col, int LD) {
  return base + row * LD + ((((col >> 3) ^ (row & 7)) << 3) | (col & 7));
}

// ---- prep: convert+pad all weights/biases into ws (single launch) ----------
__global__ void prep_weights(const float* __restrict__ W1c, const float* __restrict__ W2c,
                             const float* __restrict__ W1o, const float* __restrict__ W2o,
                             const float* __restrict__ W1p, const float* __restrict__ W2p,
                             const float* __restrict__ Wh,
                             const float* __restrict__ b1c, const float* __restrict__ b1o,
                             const float* __restrict__ b1p,
                             char* __restrict__ ws) {
  int s = blockIdx.x * 256 + threadIdx.x;
  if (s < 960512) {                      // bf16 weight region (shorts)
    float v;
    if (s < 278528)      { int n = s >> 9,        k = s & 511;        v = (n < 513) ? W1c[n * 512 + k] : 0.f; }
    else if (s < 417792) { int i = s - 278528; int n = i / 544, k = i - n * 544; v = (k < 513) ? W2c[n * 513 + k] : 0.f; }
    else if (s < 696320) { int i = s - 417792; int n = i >> 9,  k = i & 511;     v = (n < 513) ? W1o[n * 512 + k] : 0.f; }
    else if (s < 835584) { int i = s - 696320; int n = i / 544, k = i - n * 544; v = (k < 513) ? W2o[n * 513 + k] : 0.f; }
    else if (s < 909312) { int i = s - 835584; int n = i >> 8,  k = i & 255;     v = (n < 257) ? W1p[n * 256 + k] : 0.f; }
    else if (s < 927744) { int i = s - 909312; int n = i / 288, k = i - n * 288; v = (k < 257) ? W2p[n * 257 + k] : 0.f; }
    else                 { v = Wh[s - 927744]; }
    ((short*)ws)[s] = f2bf(v);
  } else if (s < 961888) {               // padded f32 biases
    int j = s - 960512;
    float v;
    if (j < 544)       v = (j < 513) ? b1c[j] : 0.f;
    else if (j < 1088) { int q = j - 544;  v = (q < 513) ? b1o[q] : 0.f; }
    else               { int q = j - 1088; v = (q < 257) ? b1p[q] : 0.f; }
    ((float*)(ws + 1921024))[j] = v;
  }
}

// paired 2x16-col tile over 4 row-groups (swizzled A).
template<int NKT>
__device__ __forceinline__ void pair_mm(const short* __restrict__ W, int ldw,
                                        const short* __restrict__ A, int lda,
                                        int nt0, int l15, int l4,
                                        f32x4 (&acc0)[4], f32x4 (&acc1)[4]) {
  const short* w0 = W + (nt0 * 16 + l15) * ldw + l4 * 8;
  const short* w1 = w0 + 16 * ldw;
  #pragma unroll
  for (int g = 0; g < 4; ++g) {
    acc0[g] = (f32x4){0.f, 0.f, 0.f, 0.f};
    acc1[g] = (f32x4){0.f, 0.f, 0.f, 0.f};
  }
  #pragma unroll
  for (int kt = 0; kt < NKT; ++kt) {
    bf16x8 b0 = *(const bf16x8*)(w0 + kt * 32);
    bf16x8 b1 = *(const bf16x8*)(w1 + kt * 32);
    #pragma unroll
    for (int g = 0; g < 4; ++g) {
      bf16x8 a = *ldsRd8(A, g * 16 + l15, kt * 4 + l4, lda);
      acc0[g] = MFMA16(a, b0, acc0[g], 0, 0, 0);
      acc1[g] = MFMA16(a, b1, acc1[g], 0, 0, 0);
    }
  }
}

__device__ __forceinline__ void store_tile(short* __restrict__ dst, int ldd, int nt,
                                           const float* __restrict__ bias,
                                           const f32x4 (&acc)[4], int l15, int l4,
                                           bool relu) {
  float bi = bias[nt * 16 + l15];
  #pragma unroll
  for (int g = 0; g < 4; ++g)
    #pragma unroll
    for (int r = 0; r < 4; ++r) {
      float v = acc[g][r] + bi;
      if (relu) v = fmaxf(v, 0.f);
      *ldsPtr(dst, g * 16 + l4 * 4 + r, nt * 16 + l15, ldd) = f2bf(v);
    }
}

// single 16-col tile, ONE row-group rg (tail quarter-jobs)
template<int NKT>
__device__ __forceinline__ void single_mm_rg(const short* __restrict__ W, int ldw,
                                             const short* __restrict__ A, int lda,
                                             int nt, int rg, int l15, int l4,
                                             short* __restrict__ dst, int ldd,
                                             const float* __restrict__ bias) {
  f32x4 acc = {0.f, 0.f, 0.f, 0.f};
  const short* w0 = W + (nt * 16 + l15) * ldw + l4 * 8;
  #pragma unroll
  for (int kt = 0; kt < NKT; ++kt) {
    bf16x8 b = *(const bf16x8*)(w0 + kt * 32);
    bf16x8 a = *ldsRd8(A, rg * 16 + l15, kt * 4 + l4, lda);
    acc = MFMA16(a, b, acc, 0, 0, 0);
  }
  float bi = bias[nt * 16 + l15];
  #pragma unroll
  for (int r = 0; r < 4; ++r)
    *ldsPtr(dst, rg * 16 + l4 * 4 + r, nt * 16 + l15, ldd) = f2bf(fmaxf(acc[r] + bi, 0.f));
}

// zero one 16-col tile for one row-group
__device__ __forceinline__ void zero_tile_rg(short* __restrict__ dst, int ldd,
                                             int nt, int rg, int l15, int l4) {
  #pragma unroll
  for (int r = 0; r < 4; ++r)
    *ldsPtr(dst, rg * 16 + l4 * 4 + r, nt * 16 + l15, ldd) = 0;
}

__global__ __launch_bounds__(512, 1)
void fused_main(const float* __restrict__ x, const int* __restrict__ cause,
                const char* __restrict__ ws,
                const float* __restrict__ b2c, const float* __restrict__ b2o,
                const float* __restrict__ b2p, const float* __restrict__ bh,
                float* __restrict__ out) {
  const short* W1cb = (const short*)(ws);
  const short* W2cb = (const short*)(ws + 557056);
  const short* W1ob = (const short*)(ws + 835584);
  const short* W2ob = (const short*)(ws + 1392640);
  const short* W1pb = (const short*)(ws + 1671168);
  const short* W2pb = (const short*)(ws + 1818624);
  const short* Whb  = (const short*)(ws + 1855488);
  const float* b1cp = (const float*)(ws + 1921024);
  const float* b1op = (const float*)(ws + 1923200);
  const float* b1pp = (const float*)(ws + 1925376);

  extern __shared__ __align__(16) char lds[];
  short* Cs    = (short*)lds;             // [64][256]
  short* Os    = (short*)(lds + 32768);   // [64][256]
  short* Hs    = (short*)(lds + 65536);   // [64][576]
  short* Xs    = (short*)lds;             // [64][512] overlays Cs|Os exactly
  float* headB = (float*)(lds + 65536);   // [64][68] f32 (after Hs dead)
  short* Hp    = (short*)(lds + 65536);   // [64][320]    (after headB dead)

  const int tid  = threadIdx.x;
  const int lane = tid & 63;
  const int wid  = tid >> 6;             // 0..7
  const int l15  = lane & 15;
  const int l4   = lane >> 4;            // 0..3
  const size_t grow0 = (size_t)blockIdx.x * 64;

  // ---- stage X (f32 -> bf16, swizzled), nontemporal ----
  {
    const f32x4* xsrc = (const f32x4*)(x + grow0 * 512);
    for (int i = tid; i < 8192; i += 512) {   // 64 rows * 128 float4
      f32x4 v = __builtin_nontemporal_load(xsrc + i);
      int r = i >> 7, c = i & 127;
      s16x4 p;
      p.x = f2bf(v.x); p.y = f2bf(v.y); p.z = f2bf(v.z); p.w = f2bf(v.w);
      int grp = (c >> 1) ^ (r & 7);       // 16B group = 2 float4-cols
      *(s16x4*)(Xs + r * 512 + (grp << 3) + ((c & 1) << 2)) = p;
    }
  }
  __syncthreads();   // B0: X staged

  // ---- L1c: Hs = relu(X @ W1c^T + b1c); 16 pairs (2/wave) + tail jobs ----
  for (int p = wid; p < 16; p += 8) {
    f32x4 a0[4], a1[4];
    pair_mm<16>(W1cb, 512, Xs, 512, 2 * p, l15, l4, a0, a1);
    store_tile(Hs, 576, 2 * p,     b1cp, a0, l15, l4, true);
    store_tile(Hs, 576, 2 * p + 1, b1cp, a1, l15, l4, true);
  }
  if (wid < 4)  // tile 32 (only row 512 real; 513-527 auto-zero via padded W)
    single_mm_rg<16>(W1cb, 512, Xs, 512, 32, wid, l15, l4, Hs, 576, b1cp);
  else          // tile 33: all-zero (rows 528-543 of padded H1)
    zero_tile_rg(Hs, 576, 33, wid - 4, l15, l4);
  __syncthreads();   // B1: H_c complete

  // ---- L2c: crep = Hs @ W2c^T + b2c; 8 pairs = 1/wave; kept in regs ----
  s16x4 crp[2][4];   // [jj][g]: nt = 2*wid + jj
  {
    f32x4 a0[4], a1[4];
    pair_mm<17>(W2cb, 544, Hs, 576, 2 * wid, l15, l4, a0, a1);
    float bi0 = b2c[wid * 32 + l15], bi1 = b2c[wid * 32 + 16 + l15];
    #pragma unroll
    for (int g = 0; g < 4; ++g) {
      s16x4 q0, q1;
      #pragma unroll
      for (int r = 0; r < 4; ++r) {
        q0[r] = f2bf(a0[g][r] + bi0);
        q1[r] = f2bf(a1[g][r] + bi1);
      }
      crp[0][g] = q0; crp[1][g] = q1;
    }
  }
  __syncthreads();   // B2: Hs reads done -> L1o may overwrite

  // ---- L1o: Hs = relu(X @ W1o^T + b1o); roles mirrored for tail ----
  for (int p = wid; p < 16; p += 8) {
    f32x4 a0[4], a1[4];
    pair_mm<16>(W1ob, 512, Xs, 512, 2 * p, l15, l4, a0, a1);
    store_tile(Hs, 576, 2 * p,     b1op, a0, l15, l4, true);
    store_tile(Hs, 576, 2 * p + 1, b1op, a1, l15, l4, true);
  }
  if (wid >= 4)
    single_mm_rg<16>(W1ob, 512, Xs, 512, 32, wid - 4, l15, l4, Hs, 576, b1op);
  else
    zero_tile_rg(Hs, 576, 33, wid, l15, l4);
  __syncthreads();   // B3: H_o complete; Xs dead everywhere

  // ---- flush crep -> Cs (region now free) ----
  #pragma unroll
  for (int jj = 0; jj < 2; ++jj) {
    int nt = 2 * wid + jj;
    #pragma unroll
    for (int g = 0; g < 4; ++g)
      #pragma unroll
      for (int r = 0; r < 4; ++r)
        *ldsPtr(Cs, g * 16 + l4 * 4 + r, nt * 16 + l15, 256) = crp[jj][g][r];
  }

  // ---- L2o: Os = Hs @ W2o^T + b2o; 1 pair/wave ----
  {
    f32x4 a0[4], a1[4];
    pair_mm<17>(W2ob, 544, Hs, 576, 2 * wid, l15, l4, a0, a1);
    store_tile(Os, 256, 2 * wid,     b2o, a0, l15, l4, false);
    store_tile(Os, 256, 2 * wid + 1, b2o, a1, l15, l4, false);
  }
  __syncthreads();   // B4: Cs+Os complete; Hs dead

  // ---- head: wave pair (g = wid>>1) shares 16-row group, splits 4 nt 2/2 --
  {
    const int g = wid >> 1;
    const int rb = g * 16;
    const int ntb = (wid & 1) * 2;
    bf16x8 acf[16];
    #pragma unroll
    for (int kt = 0; kt < 8; ++kt) {
      acf[kt]     = *ldsRd8(Cs, rb + l15, kt * 4 + l4, 256);
      acf[kt + 8] = *ldsRd8(Os, rb + l15, kt * 4 + l4, 256);
    }
    f32x4 hacc[2] = {{0.f,0.f,0.f,0.f},{0.f,0.f,0.f,0.f}};
    #pragma unroll
    for (int j = 0; j < 2; ++j) {
      const short* w0 = Whb + ((ntb + j) * 16 + l15) * 512 + l4 * 8;
      #pragma unroll
      for (int kt = 0; kt < 16; ++kt)
        hacc[j] = MFMA16(acf[kt], *(const bf16x8*)(w0 + kt * 32), hacc[j], 0, 0, 0);
    }
    // headB overlays Hs region (dead after B4); unswizzled f32
    #pragma unroll
    for (int j = 0; j < 2; ++j)
      #pragma unroll
      for (int r = 0; r < 4; ++r)
        headB[(rb + l4 * 4 + r) * 68 + (ntb + j) * 16 + l15] = hacc[j][r];
  }
  __syncthreads();   // B5: headB complete (nt halves from both waves of pair)

  // one-hot selection + cause passthrough: waves 0..3 handle 16 rows each
  if (wid < 4 && lane < 16) {
    int row = wid * 16 + lane;
    size_t gr = grow0 + row;
    int cv = cause[gr];
    out[gr] = headB[row * 68 + cv] + bh[cv];
    out[(size_t)8519681 + gr] = (float)cv;
  }
  __syncthreads();   // B6: selection reads done -> Hp may overwrite

  // ---- propensity L1: Hp = relu(Cs @ W1p^T + b1p); 8 pairs + tail jobs ----
  {
    f32x4 a0[4], a1[4];
    pair_mm<8>(W1pb, 256, Cs, 256, 2 * wid, l15, l4, a0, a1);
    store_tile(Hp, 320, 2 * wid,     b1pp, a0, l15, l4, true);
    store_tile(Hp, 320, 2 * wid + 1, b1pp, a1, l15, l4, true);
  }
  if (wid < 4)  // tile 16 (only row 256 real; 257-271 auto-zero)
    single_mm_rg<8>(W1pb, 256, Cs, 256, 16, wid, l15, l4, Hp, 320, b1pp);
  else          // tile 17: all-zero
    zero_tile_rg(Hp, 320, 17, wid - 4, l15, l4);
  __syncthreads();   // B7: Hp complete

  // ---- propensity L2 + log_softmax: waves 0..3, one 16-row group each ----
  if (wid < 4) {
    const int rb = wid * 16;
    f32x4 pl[4];
    {
      bf16x8 ahp[9];
      #pragma unroll
      for (int kt = 0; kt < 9; ++kt)
        ahp[kt] = *ldsRd8(Hp, rb + l15, kt * 4 + l4, 320);
      #pragma unroll
      for (int nt = 0; nt < 4; ++nt) {
        f32x4 a0 = {0.f, 0.f, 0.f, 0.f};
        const short* w0 = W2pb + (nt * 16 + l15) * 288 + l4 * 8;
        #pragma unroll
        for (int kt = 0; kt < 9; ++kt)
          a0 = MFMA16(ahp[kt], *(const bf16x8*)(w0 + kt * 32), a0, 0, 0, 0);
        float bi = b2p[nt * 16 + l15];
        #pragma unroll
        for (int r = 0; r < 4; ++r) a0[r] += bi;
        pl[nt] = a0;
      }
    }
    #pragma unroll
    for (int r = 0; r < 4; ++r) {
      float m = fmaxf(fmaxf(pl[0][r], pl[1][r]), fmaxf(pl[2][r], pl[3][r]));
      m = fmaxf(m, __shfl_xor(m, 1, 64));
      m = fmaxf(m, __shfl_xor(m, 2, 64));
      m = fmaxf(m, __shfl_xor(m, 4, 64));
      m = fmaxf(m, __shfl_xor(m, 8, 64));
      float s = __expf(pl[0][r] - m) + __expf(pl[1][r] - m)
              + __expf(pl[2][r] - m) + __expf(pl[3][r] - m);
      s += __shfl_xor(s, 1, 64);
      s += __shfl_xor(s, 2, 64);
      s += __shfl_xor(s, 4, 64);
      s += __shfl_xor(s, 8, 64);
      float lse = m + __logf(s);
      size_t gr = grow0 + rb + l4 * 4 + r;
      float* o1 = out + 131072 + gr * 64;
      #pragma unroll
      for (int nt = 0; nt < 4; ++nt)
        o1[nt * 16 + l15] = pl[nt][r] - lse;
    }
  }
  if (blockIdx.x == 0 && tid == 0) out[8519680] = 0.0f;   // mmd
}

extern "C" void kernel_launch(void* const* d_in, const int* in_sizes, int n_in,
                              void* d_out, int out_size, void* d_ws, size_t ws_size,
                              hipStream_t stream) {
  (void)in_sizes; (void)n_in; (void)out_size; (void)ws_size;
  const float* x    = (const float*)d_in[0];
  const int*   cause= (const int*)  d_in[1];
  const float* W1c  = (const float*)d_in[2];
  const float* b1c  = (const float*)d_in[3];
  const float* W2c  = (const float*)d_in[4];
  const float* b2c  = (const float*)d_in[5];
  const float* W1o  = (const float*)d_in[6];
  const float* b1o  = (const float*)d_in[7];
  const float* W2o  = (const float*)d_in[8];
  const float* b2o  = (const float*)d_in[9];
  const float* W1p  = (const float*)d_in[10];
  const float* b1p  = (const float*)d_in[11];
  const float* W2p  = (const float*)d_in[12];
  const float* b2p  = (const float*)d_in[13];
  const float* Wh   = (const float*)d_in[14];
  const float* bh   = (const float*)d_in[15];
  char* ws = (char*)d_ws;

  prep_weights<<<3758, 256, 0, stream>>>(W1c, W2c, W1o, W2o, W1p, W2p, Wh,
                                         b1c, b1o, b1p, ws);

  (void)hipFuncSetAttribute((const void*)fused_main,
                            hipFuncAttributeMaxDynamicSharedMemorySize, 139264);
  fused_main<<<2048, 512, 139264, stream>>>(x, cause, ws, b2c, b2o, b2p, bh,
                                            (float*)d_out);
}